// Round 1
// baseline (2312.748 us; speedup 1.0000x reference)
//
#include <hip/hip_runtime.h>
#include <stdint.h>

#define DIM  1024
#define NB   8
#define NSEQ 1024
#define NP   77
#define NH   16
#define NKV  1101      // P + N
#define WPAD 1104      // padded weight row length (multiple of 4)

typedef short          bf16x8 __attribute__((ext_vector_type(8)));
typedef float          f32x4  __attribute__((ext_vector_type(4)));
typedef unsigned short u16x8  __attribute__((ext_vector_type(8)));
typedef unsigned short u16x4  __attribute__((ext_vector_type(4)));

__device__ __forceinline__ float bf2f(unsigned short h) {
  return __uint_as_float(((unsigned int)h) << 16);
}
__device__ __forceinline__ unsigned short f2bf(float f) {
  unsigned int u = __float_as_uint(f);
  unsigned int r = u + 0x7FFFu + ((u >> 16) & 1u);   // RNE
  return (unsigned short)(r >> 16);
}

// ---------------------------------------------------------------- casts
__global__ __launch_bounds__(256) void cast_kernel(const float* __restrict__ in,
                                                   unsigned short* __restrict__ out,
                                                   int n4) {
  int i = blockIdx.x * 256 + threadIdx.x;
  if (i >= n4) return;
  float4 v = reinterpret_cast<const float4*>(in)[i];
  u16x4 o;
  o[0] = f2bf(v.x); o[1] = f2bf(v.y); o[2] = f2bf(v.z); o[3] = f2bf(v.w);
  reinterpret_cast<u16x4*>(out)[i] = o;
}

// ------------------------------------------------------- async global->LDS
__device__ __forceinline__ void gload_lds16(const void* g, void* l) {
  __builtin_amdgcn_global_load_lds(
      (const __attribute__((address_space(1))) void*)g,
      (__attribute__((address_space(3))) void*)l, 16, 0, 0);
}

// ---------------------------------------------------------------- GEMM
// C[drow(m), n] = sum_k A[m,k] * B[n,k]   (+ bias[n])
// drow(m) = (m / rpb_in) * rpb_out + row_off + (m % rpb_in)
// 128x128 tile, BK=32, 256 threads (4 waves, 2x2), mfma_f32_16x16x32_bf16.
template<bool OUT_BF16, bool BIAS>
__global__ __launch_bounds__(256) void gemm_bt(
    const unsigned short* __restrict__ A, const unsigned short* __restrict__ B,
    void* __restrict__ C, const float* __restrict__ bias,
    int M, int Nn, int Kk, int rpb_in, int rpb_out, int row_off, int ldc) {
  __shared__ __align__(16) unsigned short As[128 * 32];
  __shared__ __align__(16) unsigned short Bs[128 * 32];
  const int t    = threadIdx.x;
  const int w    = t >> 6;
  const int lane = t & 63;
  const int m0   = blockIdx.x * 128;
  const int n0   = blockIdx.y * 128;
  const int wr   = w >> 1, wc = w & 1;
  const int lr   = lane & 15;
  const int k0   = (lane >> 4) * 8;

  f32x4 acc[4][4];
#pragma unroll
  for (int i = 0; i < 4; ++i)
#pragma unroll
    for (int j = 0; j < 4; ++j) acc[i][j] = f32x4{0.f, 0.f, 0.f, 0.f};

  const int nkt = Kk >> 5;
  for (int kt = 0; kt < nkt; ++kt) {
#pragma unroll
    for (int p = 0; p < 2; ++p) {
      const int c   = p * 256 + t;
      const int row = c >> 2;
      const int cid = c & 3;
      int ar = m0 + row; ar = ar < M ? ar : M - 1;
      gload_lds16(A + (size_t)ar * Kk + kt * 32 + cid * 8,
                  (char*)As + p * 4096 + w * 1024);
      int br = n0 + row; br = br < Nn ? br : Nn - 1;
      gload_lds16(B + (size_t)br * Kk + kt * 32 + cid * 8,
                  (char*)Bs + p * 4096 + w * 1024);
    }
    __syncthreads();
    bf16x8 af[4], bf[4];
#pragma unroll
    for (int mi = 0; mi < 4; ++mi)
      af[mi] = *reinterpret_cast<const bf16x8*>(As + (wr * 64 + mi * 16 + lr) * 32 + k0);
#pragma unroll
    for (int ni = 0; ni < 4; ++ni)
      bf[ni] = *reinterpret_cast<const bf16x8*>(Bs + (wc * 64 + ni * 16 + lr) * 32 + k0);
#pragma unroll
    for (int mi = 0; mi < 4; ++mi)
#pragma unroll
      for (int ni = 0; ni < 4; ++ni)
        acc[mi][ni] = __builtin_amdgcn_mfma_f32_16x16x32_bf16(af[mi], bf[ni], acc[mi][ni], 0, 0, 0);
    __syncthreads();
  }

  const int rq = lane >> 4;
#pragma unroll
  for (int mi = 0; mi < 4; ++mi) {
#pragma unroll
    for (int i = 0; i < 4; ++i) {
      const int m = m0 + wr * 64 + mi * 16 + rq * 4 + i;
      if (m >= M) continue;
      const int drow = (m / rpb_in) * rpb_out + row_off + (m % rpb_in);
#pragma unroll
      for (int ni = 0; ni < 4; ++ni) {
        const int col = n0 + wc * 64 + ni * 16 + lr;
        float v = acc[mi][ni][i];
        if (BIAS) v += bias[col];
        const size_t idx = (size_t)drow * ldc + col;
        if (OUT_BF16) ((unsigned short*)C)[idx] = f2bf(v);
        else          ((float*)C)[idx] = v;
      }
    }
  }
}

// ---------------------------------------------------------------- attention
// grid (128, B*H), block 128 (2 waves). Each wave: 4 q-rows of one (b,h).
// Scores: lane-owns-key; softmax weights staged in LDS; AV: lane-owns-d.
__global__ __launch_bounds__(128) void attn_kernel(
    const unsigned short* __restrict__ Q, const unsigned short* __restrict__ K,
    const unsigned short* __restrict__ V, const float* __restrict__ gate,
    unsigned short* __restrict__ O) {
  const int wid  = threadIdx.x >> 6;
  const int lane = threadIdx.x & 63;
  const int bh   = blockIdx.y;
  const int b    = bh >> 4;
  const int h    = bh & 15;
  const int n0   = blockIdx.x * 8 + wid * 4;

  __shared__ __align__(16) float q_lds[2][4][64];
  __shared__ __align__(16) float w_lds[2][4][WPAD];

#pragma unroll
  for (int r = 0; r < 4; ++r)
    q_lds[wid][r][lane] = bf2f(Q[((size_t)(b * NSEQ + n0 + r)) * DIM + h * 64 + lane]);
  __syncthreads();

  // ---- scores: lane l owns keys l, l+64, ... (18 batches cover 1101)
  const unsigned short* Kbase = K + ((size_t)b * NKV) * DIM + h * 64;
  for (int kb = 0; kb < 18; ++kb) {
    const int j  = kb * 64 + lane;
    const int jc = j < NKV ? j : (NKV - 1);
    const unsigned short* kr = Kbase + (size_t)jc * DIM;
    float sacc[4] = {0.f, 0.f, 0.f, 0.f};
#pragma unroll
    for (int d0 = 0; d0 < 64; d0 += 8) {
      const u16x8 kv = *reinterpret_cast<const u16x8*>(kr + d0);
      float kf[8];
#pragma unroll
      for (int e = 0; e < 8; ++e) kf[e] = bf2f(kv[e]);
#pragma unroll
      for (int r = 0; r < 4; ++r) {
        const float4 qa = *reinterpret_cast<const float4*>(&q_lds[wid][r][d0]);
        const float4 qb = *reinterpret_cast<const float4*>(&q_lds[wid][r][d0 + 4]);
        sacc[r] += qa.x * kf[0] + qa.y * kf[1] + qa.z * kf[2] + qa.w * kf[3]
                 + qb.x * kf[4] + qb.y * kf[5] + qb.z * kf[6] + qb.w * kf[7];
      }
    }
    if (j < WPAD) {
#pragma unroll
      for (int r = 0; r < 4; ++r) w_lds[wid][r][j] = sacc[r] * 0.125f;
    }
  }

  // ---- gated split softmax (key 0 -> tanh(gate[h]); softmax over 1..1100)
  const float gv = tanhf(gate[h]);
  for (int r = 0; r < 4; ++r) {
    float mx = -1e30f;
    for (int kb = 0; kb < 18; ++kb) {
      const int j = kb * 64 + lane;
      if (j >= 1 && j < NKV) mx = fmaxf(mx, w_lds[wid][r][j]);
    }
    for (int off = 32; off; off >>= 1) mx = fmaxf(mx, __shfl_xor(mx, off));
    float sm = 0.f;
    for (int kb = 0; kb < 18; ++kb) {
      const int j = kb * 64 + lane;
      float e = 0.f;
      if (j >= 1 && j < NKV) {
        e = __expf(w_lds[wid][r][j] - mx);
        w_lds[wid][r][j] = e;
      } else if (j >= NKV && j < WPAD) {
        w_lds[wid][r][j] = 0.f;
      }
      sm += e;
    }
    for (int off = 32; off; off >>= 1) sm += __shfl_xor(sm, off);
    const float inv = 1.f / sm;
    for (int kb = 0; kb < 18; ++kb) {
      const int j = kb * 64 + lane;
      if (j >= 1 && j < NKV) w_lds[wid][r][j] *= inv;
    }
    if (lane == 0) w_lds[wid][r][0] = gv;
  }
  __syncthreads();

  // ---- AV: lane owns output dim d = lane
  float outa[4] = {0.f, 0.f, 0.f, 0.f};
  const unsigned short* Vb = V + ((size_t)b * NKV) * DIM + h * 64 + lane;
  for (int c = 0; c < WPAD / 4; ++c) {
    const int j = c * 4;
    float vv[4];
#pragma unroll
    for (int u = 0; u < 4; ++u) {
      const int jc = (j + u) < NKV ? (j + u) : (NKV - 1);
      vv[u] = bf2f(Vb[(size_t)jc * DIM]);
    }
#pragma unroll
    for (int r = 0; r < 4; ++r) {
      const float4 w4 = *reinterpret_cast<const float4*>(&w_lds[wid][r][j]);
      outa[r] += w4.x * vv[0] + w4.y * vv[1] + w4.z * vv[2] + w4.w * vv[3];
    }
  }
#pragma unroll
  for (int r = 0; r < 4; ++r)
    O[((size_t)(b * NSEQ + n0 + r)) * DIM + h * 64 + lane] = f2bf(outa[r]);
}

// ---------------------------------------------------------------- LayerNorm
__global__ __launch_bounds__(256) void ln_kernel(const unsigned short* __restrict__ in,
                                                 const float* __restrict__ g,
                                                 const float* __restrict__ beta,
                                                 unsigned short* __restrict__ out) {
  const int row = blockIdx.x;
  const int t   = threadIdx.x;
  const u16x4 hv = *reinterpret_cast<const u16x4*>(in + (size_t)row * DIM + t * 4);
  const float v0 = bf2f(hv[0]), v1 = bf2f(hv[1]), v2 = bf2f(hv[2]), v3 = bf2f(hv[3]);
  float sum = v0 + v1 + v2 + v3;
  float sq  = v0 * v0 + v1 * v1 + v2 * v2 + v3 * v3;
  for (int off = 32; off; off >>= 1) {
    sum += __shfl_xor(sum, off);
    sq  += __shfl_xor(sq, off);
  }
  __shared__ float red[8];
  if ((t & 63) == 0) { red[t >> 6] = sum; red[4 + (t >> 6)] = sq; }
  __syncthreads();
  sum = red[0] + red[1] + red[2] + red[3];
  sq  = red[4] + red[5] + red[6] + red[7];
  const float mu  = sum * (1.f / DIM);
  const float var = sq * (1.f / DIM) - mu * mu;
  const float rs  = 1.f / sqrtf(var + 1e-5f);
  const float4 gv = *reinterpret_cast<const float4*>(g + t * 4);
  const float4 bv = *reinterpret_cast<const float4*>(beta + t * 4);
  u16x4 o;
  o[0] = f2bf((v0 - mu) * rs * gv.x + bv.x);
  o[1] = f2bf((v1 - mu) * rs * gv.y + bv.y);
  o[2] = f2bf((v2 - mu) * rs * gv.z + bv.z);
  o[3] = f2bf((v3 - mu) * rs * gv.w + bv.w);
  *reinterpret_cast<u16x4*>(out + (size_t)row * DIM + t * 4) = o;
}

// ---------------------------------------------------------------- launch
extern "C" void kernel_launch(void* const* d_in, const int* in_sizes, int n_in,
                              void* d_out, int out_size, void* d_ws, size_t ws_size,
                              hipStream_t stream) {
  const float* x    = (const float*)d_in[0];
  const float* xt   = (const float*)d_in[1];
  const float* Wq   = (const float*)d_in[2];
  const float* Wk   = (const float*)d_in[3];
  const float* Wv   = (const float*)d_in[4];
  const float* gate = (const float*)d_in[5];
  const float* lng  = (const float*)d_in[6];
  const float* lnbt = (const float*)d_in[7];
  const float* Wp   = (const float*)d_in[8];
  const float* bp   = (const float*)d_in[9];

  char* ws = (char*)d_ws;
  unsigned short* xb  = (unsigned short*)(ws + 0);          // 16,777,216 B
  unsigned short* xtb = (unsigned short*)(ws + 16777216);   //  1,261,568 B
  unsigned short* Wqb = (unsigned short*)(ws + 18038784);   //  2,097,152 B
  unsigned short* Wkb = (unsigned short*)(ws + 20135936);
  unsigned short* Wvb = (unsigned short*)(ws + 22233088);
  unsigned short* Wpb = (unsigned short*)(ws + 24330240);
  unsigned short* Qb  = (unsigned short*)(ws + 26427392);   // 16,777,216 B
  unsigned short* Kb  = (unsigned short*)(ws + 43204608);   // 18,038,784 B
  unsigned short* Vb  = (unsigned short*)(ws + 61243392);   // 18,038,784 B  (end 79,282,176)
  unsigned short* attnb = xb;   // x is dead after projections (stream-ordered)
  unsigned short* lnob  = Qb;   // Q is dead after attention

  auto cast = [&](const float* src, unsigned short* dst, int n) {
    const int n4 = n >> 2;
    cast_kernel<<<dim3((n4 + 255) / 256), dim3(256), 0, stream>>>(src, dst, n4);
  };
  cast(x,  xb,  NB * NSEQ * DIM);
  cast(xt, xtb, NB * NP * DIM);
  cast(Wq, Wqb, DIM * DIM);
  cast(Wk, Wkb, DIM * DIM);
  cast(Wv, Wvb, DIM * DIM);
  cast(Wp, Wpb, DIM * DIM);

  // Q = x Wq^T  -> [8192, 1024]
  gemm_bt<true, false><<<dim3(64, 8), 256, 0, stream>>>(
      xb, Wqb, Qb, nullptr, NB * NSEQ, DIM, DIM, NSEQ, NSEQ, 0, DIM);
  // K = [x_text Wk^T ; x Wk^T] -> [8*1101, 1024]
  gemm_bt<true, false><<<dim3(5, 8), 256, 0, stream>>>(
      xtb, Wkb, Kb, nullptr, NB * NP, DIM, DIM, NP, NKV, 0, DIM);
  gemm_bt<true, false><<<dim3(64, 8), 256, 0, stream>>>(
      xb, Wkb, Kb, nullptr, NB * NSEQ, DIM, DIM, NSEQ, NKV, NP, DIM);
  // V likewise
  gemm_bt<true, false><<<dim3(5, 8), 256, 0, stream>>>(
      xtb, Wvb, Vb, nullptr, NB * NP, DIM, DIM, NP, NKV, 0, DIM);
  gemm_bt<true, false><<<dim3(64, 8), 256, 0, stream>>>(
      xb, Wvb, Vb, nullptr, NB * NSEQ, DIM, DIM, NSEQ, NKV, NP, DIM);

  attn_kernel<<<dim3(128, NB * NH), 128, 0, stream>>>(Qb, Kb, Vb, gate, attnb);
  ln_kernel<<<dim3(NB * NSEQ), 256, 0, stream>>>(attnb, lng, lnbt, lnob);
  // out = LN(attn) Wp^T + bp  (f32 out)
  gemm_bt<false, true><<<dim3(64, 8), 256, 0, stream>>>(
      lnob, Wpb, d_out, bp, NB * NSEQ, DIM, DIM, NSEQ, NSEQ, 0, DIM);
}

// Round 3
// 345.959 us; speedup vs baseline: 6.6850x; 6.6850x over previous
//
#include <hip/hip_runtime.h>
#include <stdint.h>

#define DIM   1024
#define NB    8
#define NSEQ  1024
#define NP    77
#define NH    16
#define NKVR  1104     // padded key space: text 0..76, hole 77..79, x 80..1103
#define KVP   1104     // Vt row length (kv), multiple of 8
#define NTILE 18       // ceil(1152/64) key tiles of 64

typedef short          bf16x8 __attribute__((ext_vector_type(8)));
typedef float          f32x4  __attribute__((ext_vector_type(4)));
typedef unsigned short u16x8  __attribute__((ext_vector_type(8)));
typedef unsigned short u16x4  __attribute__((ext_vector_type(4)));

__device__ __forceinline__ float bf2f(unsigned short h) {
  return __uint_as_float(((unsigned int)h) << 16);
}
__device__ __forceinline__ unsigned short f2bf(float f) {
  unsigned int u = __float_as_uint(f);
  unsigned int r = u + 0x7FFFu + ((u >> 16) & 1u);   // RNE
  return (unsigned short)(r >> 16);
}

// ---------------------------------------------------------------- casts
__global__ __launch_bounds__(256) void cast_kernel(const float* __restrict__ in,
                                                   unsigned short* __restrict__ out,
                                                   int n4) {
  int i = blockIdx.x * 256 + threadIdx.x;
  if (i >= n4) return;
  float4 v = reinterpret_cast<const float4*>(in)[i];
  u16x4 o;
  o[0] = f2bf(v.x); o[1] = f2bf(v.y); o[2] = f2bf(v.z); o[3] = f2bf(v.w);
  reinterpret_cast<u16x4*>(out)[i] = o;
}

// zero the V-transpose hole columns (kv 77..79) for NaN safety
__global__ __launch_bounds__(256) void zero_vt_hole(unsigned short* __restrict__ Vt) {
  int row = blockIdx.x * 256 + threadIdx.x;   // 8192 d-rows total (B*H*64)
  if (row >= NB * NH * 64) return;
  unsigned short* p = Vt + (size_t)row * KVP + 77;
  p[0] = 0; p[1] = 0; p[2] = 0;
}

// ------------------------------------------------------- async global->LDS
__device__ __forceinline__ void gload_lds16(const void* g, void* l) {
  __builtin_amdgcn_global_load_lds(
      (const __attribute__((address_space(1))) void*)g,
      (__attribute__((address_space(3))) void*)l, 16, 0, 0);
}

// ---------------------------------------------------------------- GEMM
// C = A * B^T (+bias). MODE 0: f32 row-major, rows remapped.
//                      MODE 1: bf16 row-major, rows remapped.
//                      MODE 2: bf16 V-transpose write: Vt[b,h,d,kv], kv=row_off+m%rpb_in
// row remap (modes 0/1): drow = (m/rpb_in)*rpb_out + row_off + m%rpb_in
template<int MODE, bool BIAS>
__global__ __launch_bounds__(256) void gemm_bt(
    const unsigned short* __restrict__ A, const unsigned short* __restrict__ B,
    void* __restrict__ C, const float* __restrict__ bias,
    int M, int Nn, int Kk, int rpb_in, int rpb_out, int row_off, int ldc) {
  __shared__ __align__(16) unsigned short As[128 * 32];
  __shared__ __align__(16) unsigned short Bs[128 * 32];
  const int t    = threadIdx.x;
  const int w    = t >> 6;
  const int lane = t & 63;
  const int m0   = blockIdx.x * 128;
  const int n0   = blockIdx.y * 128;
  const int wr   = w >> 1, wc = w & 1;
  const int lr   = lane & 15;
  const int k0   = (lane >> 4) * 8;

  f32x4 acc[4][4];
#pragma unroll
  for (int i = 0; i < 4; ++i)
#pragma unroll
    for (int j = 0; j < 4; ++j) acc[i][j] = f32x4{0.f, 0.f, 0.f, 0.f};

  const int nkt = Kk >> 5;
  for (int kt = 0; kt < nkt; ++kt) {
#pragma unroll
    for (int p = 0; p < 2; ++p) {
      const int c   = p * 256 + t;
      const int row = c >> 2;
      const int cid = c & 3;
      int ar = m0 + row; ar = ar < M ? ar : M - 1;
      gload_lds16(A + (size_t)ar * Kk + kt * 32 + cid * 8,
                  (char*)As + p * 4096 + w * 1024);
      int br = n0 + row; br = br < Nn ? br : Nn - 1;
      gload_lds16(B + (size_t)br * Kk + kt * 32 + cid * 8,
                  (char*)Bs + p * 4096 + w * 1024);
    }
    __syncthreads();
    bf16x8 af[4], bfr[4];
#pragma unroll
    for (int mi = 0; mi < 4; ++mi)
      af[mi] = *reinterpret_cast<const bf16x8*>(As + (wr * 64 + mi * 16 + lr) * 32 + k0);
#pragma unroll
    for (int ni = 0; ni < 4; ++ni)
      bfr[ni] = *reinterpret_cast<const bf16x8*>(Bs + (wc * 64 + ni * 16 + lr) * 32 + k0);
#pragma unroll
    for (int mi = 0; mi < 4; ++mi)
#pragma unroll
      for (int ni = 0; ni < 4; ++ni)
        acc[mi][ni] = __builtin_amdgcn_mfma_f32_16x16x32_bf16(af[mi], bfr[ni], acc[mi][ni], 0, 0, 0);
    __syncthreads();
  }

  const int rq = lane >> 4;
  if (MODE == 2) {
    // V-transpose epilogue
    if (rpb_in == 1024) {
      // packed: 4 consecutive kv per thread, 8B aligned (row_off multiple of 4)
#pragma unroll
      for (int mi = 0; mi < 4; ++mi) {
        const int m = m0 + wr * 64 + mi * 16 + rq * 4;
        if (m >= M) continue;
        const int batch = m >> 10;
        const int kv    = row_off + (m & 1023);
#pragma unroll
        for (int ni = 0; ni < 4; ++ni) {
          const int col = n0 + wc * 64 + ni * 16 + lr;
          const int hh = col >> 6, dd = col & 63;
          u16x4 o;
          o[0] = f2bf(acc[mi][ni][0]); o[1] = f2bf(acc[mi][ni][1]);
          o[2] = f2bf(acc[mi][ni][2]); o[3] = f2bf(acc[mi][ni][3]);
          *reinterpret_cast<u16x4*>((unsigned short*)C +
              ((size_t)((batch * NH + hh) * 64 + dd)) * KVP + kv) = o;
        }
      }
    } else {
#pragma unroll
      for (int mi = 0; mi < 4; ++mi) {
#pragma unroll
        for (int i = 0; i < 4; ++i) {
          const int m = m0 + wr * 64 + mi * 16 + rq * 4 + i;
          if (m >= M) continue;
          const int batch = m / rpb_in;
          const int kv    = row_off + (m - batch * rpb_in);
#pragma unroll
          for (int ni = 0; ni < 4; ++ni) {
            const int col = n0 + wc * 64 + ni * 16 + lr;
            const int hh = col >> 6, dd = col & 63;
            ((unsigned short*)C)[((size_t)((batch * NH + hh) * 64 + dd)) * KVP + kv] =
                f2bf(acc[mi][ni][i]);
          }
        }
      }
    }
    return;
  }

#pragma unroll
  for (int mi = 0; mi < 4; ++mi) {
#pragma unroll
    for (int i = 0; i < 4; ++i) {
      const int m = m0 + wr * 64 + mi * 16 + rq * 4 + i;
      if (m >= M) continue;
      const int drow = (m / rpb_in) * rpb_out + row_off + (m % rpb_in);
#pragma unroll
      for (int ni = 0; ni < 4; ++ni) {
        const int col = n0 + wc * 64 + ni * 16 + lr;
        float v = acc[mi][ni][i];
        if (BIAS) v += bias[col];
        const size_t idx = (size_t)drow * ldc + col;
        if (MODE == 1) ((unsigned short*)C)[idx] = f2bf(v);
        else           ((float*)C)[idx] = v;
      }
    }
  }
}

// ---------------------------------------------------------------- MFMA attention
// grid (8, B*H), block 256 (4 waves). Wave owns 32 q-rows.
// K [b][kv(1104)][DIM] row-major bf16 (hole rows 77..79 garbage, masked).
// Vt [b][h][d(64)][KVP] bf16 (V transposed; hole cols zeroed).
// Key 0 is gated: masked in softmax, tanh(gate[h])*V0 added in epilogue.
__global__ __launch_bounds__(256) void attn_mfma(
    const unsigned short* __restrict__ Q, const unsigned short* __restrict__ K,
    const unsigned short* __restrict__ Vt, const float* __restrict__ gate,
    unsigned short* __restrict__ O) {
  const int wid  = threadIdx.x >> 6;
  const int lane = threadIdx.x & 63;
  const int lr   = lane & 15;
  const int lg   = lane >> 4;
  const int bh   = blockIdx.y;
  const int b    = bh >> 4;
  const int h    = bh & 15;
  const int q0   = blockIdx.x * 128 + wid * 32;

  __shared__ unsigned short p_lds[4][32 * 72];   // per-wave P tile, padded rows

  // Q fragments: A-layout, row = lr, k = lg*8+e  (per 32-k chunk)
  bf16x8 aq[2][2];
#pragma unroll
  for (int mi = 0; mi < 2; ++mi)
#pragma unroll
    for (int kf = 0; kf < 2; ++kf)
      aq[mi][kf] = *reinterpret_cast<const bf16x8*>(
          Q + ((size_t)(b * NSEQ + q0 + mi * 16 + lr)) * DIM + h * 64 + kf * 32 + lg * 8);

  f32x4 accO[2][4];
#pragma unroll
  for (int mi = 0; mi < 2; ++mi)
#pragma unroll
    for (int n = 0; n < 4; ++n) accO[mi][n] = f32x4{0.f, 0.f, 0.f, 0.f};
  float mrun[2][4], lrun[2][4];
#pragma unroll
  for (int mi = 0; mi < 2; ++mi)
#pragma unroll
    for (int r = 0; r < 4; ++r) { mrun[mi][r] = -3.0e38f; lrun[mi][r] = 0.f; }

  const unsigned short* Kbase  = K  + ((size_t)b * NKVR) * DIM + h * 64 + lg * 8;
  const unsigned short* Vtbase = Vt + ((size_t)((b * NH + h) * 64)) * KVP;
  unsigned short* pl = p_lds[wid];

  for (int tkv = 0; tkv < NTILE; ++tkv) {
    const int kv0 = tkv * 64;
    // ---- S = Q K^T  (D-layout: col=key=lr(+16*ni), row=q=lg*4+r(+16*mi))
    f32x4 S[2][4];
#pragma unroll
    for (int mi = 0; mi < 2; ++mi)
#pragma unroll
      for (int ni = 0; ni < 4; ++ni) S[mi][ni] = f32x4{0.f, 0.f, 0.f, 0.f};
#pragma unroll
    for (int ni = 0; ni < 4; ++ni) {
      int kvn = kv0 + ni * 16 + lr;
      kvn = kvn < (NKVR - 1) ? kvn : (NKVR - 1);
      const unsigned short* kr = Kbase + (size_t)kvn * DIM;
#pragma unroll
      for (int kf = 0; kf < 2; ++kf) {
        const bf16x8 bk = *reinterpret_cast<const bf16x8*>(kr + kf * 32);
#pragma unroll
        for (int mi = 0; mi < 2; ++mi)
          S[mi][ni] = __builtin_amdgcn_mfma_f32_16x16x32_bf16(aq[mi][kf], bk, S[mi][ni], 0, 0, 0);
      }
    }
    // ---- mask (tiles containing key 0, the hole 77..79, or tail >=1104)
    if (tkv < 2 || tkv == NTILE - 1) {
#pragma unroll
      for (int ni = 0; ni < 4; ++ni) {
        const int gk = kv0 + ni * 16 + lr;
        const bool bad = (gk == 0) || ((unsigned)(gk - 77) < 3u) || (gk >= NKVR);
        if (bad) {
#pragma unroll
          for (int mi = 0; mi < 2; ++mi)
#pragma unroll
            for (int r = 0; r < 4; ++r) S[mi][ni][r] = -1.0e30f;
        }
      }
    }
    // ---- online softmax (scale 1/8 folded into exp)
    float sf[2][4];
#pragma unroll
    for (int mi = 0; mi < 2; ++mi) {
#pragma unroll
      for (int r = 0; r < 4; ++r) {
        float tm = fmaxf(fmaxf(S[mi][0][r], S[mi][1][r]), fmaxf(S[mi][2][r], S[mi][3][r]));
        tm = fmaxf(tm, __shfl_xor(tm, 1));
        tm = fmaxf(tm, __shfl_xor(tm, 2));
        tm = fmaxf(tm, __shfl_xor(tm, 4));
        tm = fmaxf(tm, __shfl_xor(tm, 8));
        const float mn = fmaxf(mrun[mi][r], tm);
        sf[mi][r] = __expf(0.125f * (mrun[mi][r] - mn));
        mrun[mi][r] = mn;
      }
    }
#pragma unroll
    for (int mi = 0; mi < 2; ++mi) {
#pragma unroll
      for (int r = 0; r < 4; ++r) {
        const float mm = mrun[mi][r];
#pragma unroll
        for (int ni = 0; ni < 4; ++ni)
          S[mi][ni][r] = __expf(0.125f * (S[mi][ni][r] - mm));
      }
    }
#pragma unroll
    for (int mi = 0; mi < 2; ++mi) {
#pragma unroll
      for (int r = 0; r < 4; ++r) {
        float ts = (S[mi][0][r] + S[mi][1][r]) + (S[mi][2][r] + S[mi][3][r]);
        ts += __shfl_xor(ts, 1);
        ts += __shfl_xor(ts, 2);
        ts += __shfl_xor(ts, 4);
        ts += __shfl_xor(ts, 8);
        lrun[mi][r] = lrun[mi][r] * sf[mi][r] + ts;
#pragma unroll
        for (int n = 0; n < 4; ++n) accO[mi][n][r] *= sf[mi][r];
      }
    }
    // ---- P -> LDS (bf16), D-layout positions
#pragma unroll
    for (int mi = 0; mi < 2; ++mi)
#pragma unroll
      for (int ni = 0; ni < 4; ++ni)
#pragma unroll
        for (int r = 0; r < 4; ++r)
          pl[(mi * 16 + lg * 4 + r) * 72 + ni * 16 + lr] = f2bf(S[mi][ni][r]);
    // ---- O += P V  (A-frag of P from LDS, B-frag of V from Vt rows)
    bf16x8 pa[2][2];
#pragma unroll
    for (int mi = 0; mi < 2; ++mi)
#pragma unroll
      for (int kf = 0; kf < 2; ++kf)
        pa[mi][kf] = *reinterpret_cast<const bf16x8*>(pl + (mi * 16 + lr) * 72 + kf * 32 + lg * 8);
#pragma unroll
    for (int n = 0; n < 4; ++n) {
      const unsigned short* vr = Vtbase + (size_t)(n * 16 + lr) * KVP;
#pragma unroll
      for (int kf = 0; kf < 2; ++kf) {
        int kvb = kv0 + kf * 32 + lg * 8;
        kvb = kvb < (KVP - 8) ? kvb : (KVP - 8);
        const bf16x8 bv = *reinterpret_cast<const bf16x8*>(vr + kvb);
#pragma unroll
        for (int mi = 0; mi < 2; ++mi)
          accO[mi][n] = __builtin_amdgcn_mfma_f32_16x16x32_bf16(pa[mi][kf], bv, accO[mi][n], 0, 0, 0);
      }
    }
  }

  // ---- epilogue: normalize, add gated key-0 contribution, store
  const float gv = tanhf(gate[h]);
#pragma unroll
  for (int mi = 0; mi < 2; ++mi) {
#pragma unroll
    for (int n = 0; n < 4; ++n) {
      const float v0 = bf2f(Vtbase[(size_t)(n * 16 + lr) * KVP]);   // key 0
#pragma unroll
      for (int r = 0; r < 4; ++r) {
        const float o = accO[mi][n][r] / lrun[mi][r] + gv * v0;
        const int q = q0 + mi * 16 + lg * 4 + r;
        O[((size_t)(b * NSEQ + q)) * DIM + h * 64 + n * 16 + lr] = f2bf(o);
      }
    }
  }
}

// ---------------------------------------------------------------- LayerNorm
__global__ __launch_bounds__(256) void ln_kernel(const unsigned short* __restrict__ in,
                                                 const float* __restrict__ g,
                                                 const float* __restrict__ beta,
                                                 unsigned short* __restrict__ out) {
  const int row = blockIdx.x;
  const int t   = threadIdx.x;
  const u16x4 hv = *reinterpret_cast<const u16x4*>(in + (size_t)row * DIM + t * 4);
  const float v0 = bf2f(hv[0]), v1 = bf2f(hv[1]), v2 = bf2f(hv[2]), v3 = bf2f(hv[3]);
  float sum = v0 + v1 + v2 + v3;
  float sq  = v0 * v0 + v1 * v1 + v2 * v2 + v3 * v3;
  for (int off = 32; off; off >>= 1) {
    sum += __shfl_xor(sum, off);
    sq  += __shfl_xor(sq, off);
  }
  __shared__ float red[8];
  if ((t & 63) == 0) { red[t >> 6] = sum; red[4 + (t >> 6)] = sq; }
  __syncthreads();
  sum = red[0] + red[1] + red[2] + red[3];
  sq  = red[4] + red[5] + red[6] + red[7];
  const float mu  = sum * (1.f / DIM);
  const float var = sq * (1.f / DIM) - mu * mu;
  const float rs  = 1.f / sqrtf(var + 1e-5f);
  const float4 gv = *reinterpret_cast<const float4*>(g + t * 4);
  const float4 bv = *reinterpret_cast<const float4*>(beta + t * 4);
  u16x4 o;
  o[0] = f2bf((v0 - mu) * rs * gv.x + bv.x);
  o[1] = f2bf((v1 - mu) * rs * gv.y + bv.y);
  o[2] = f2bf((v2 - mu) * rs * gv.z + bv.z);
  o[3] = f2bf((v3 - mu) * rs * gv.w + bv.w);
  *reinterpret_cast<u16x4*>(out + (size_t)row * DIM + t * 4) = o;
}

// ---------------------------------------------------------------- launch
extern "C" void kernel_launch(void* const* d_in, const int* in_sizes, int n_in,
                              void* d_out, int out_size, void* d_ws, size_t ws_size,
                              hipStream_t stream) {
  const float* x    = (const float*)d_in[0];
  const float* xt   = (const float*)d_in[1];
  const float* Wq   = (const float*)d_in[2];
  const float* Wk   = (const float*)d_in[3];
  const float* Wv   = (const float*)d_in[4];
  const float* gate = (const float*)d_in[5];
  const float* lng  = (const float*)d_in[6];
  const float* lnbt = (const float*)d_in[7];
  const float* Wp   = (const float*)d_in[8];
  const float* bp   = (const float*)d_in[9];

  char* ws = (char*)d_ws;
  unsigned short* xb  = (unsigned short*)(ws + 0);          // 16,777,216
  unsigned short* xtb = (unsigned short*)(ws + 16777216);   //  1,261,568
  unsigned short* Wqb = (unsigned short*)(ws + 18038784);   //  2,097,152 (reused for Wp later)
  unsigned short* Wkb = (unsigned short*)(ws + 20135936);   //  2,097,152
  unsigned short* Wvb = (unsigned short*)(ws + 22233088);   //  2,097,152
  unsigned short* Qb  = (unsigned short*)(ws + 24330240);   // 16,777,216
  unsigned short* Kb  = (unsigned short*)(ws + 41107456);   // 18,087,936 (8*1104*1024*2)
  unsigned short* Vtb = (unsigned short*)(ws + 59195392);   // 18,087,936 (8192*1104*2) end 77,283,328
  unsigned short* attnb = xb;   // x dead after projections
  unsigned short* lnob  = Kb;   // K dead after attention
  unsigned short* Wpb   = Wqb;  // Wq dead after Q projection

  auto cast = [&](const float* src, unsigned short* dst, int n) {
    const int n4 = n >> 2;
    cast_kernel<<<dim3((n4 + 255) / 256), dim3(256), 0, stream>>>(src, dst, n4);
  };
  cast(x,  xb,  NB * NSEQ * DIM);
  cast(xt, xtb, NB * NP * DIM);
  cast(Wq, Wqb, DIM * DIM);
  cast(Wk, Wkb, DIM * DIM);
  cast(Wv, Wvb, DIM * DIM);
  zero_vt_hole<<<dim3(32), dim3(256), 0, stream>>>(Vtb);

  // Q = x Wq^T  -> [8192, 1024] bf16
  gemm_bt<1, false><<<dim3(64, 8), 256, 0, stream>>>(
      xb, Wqb, Qb, nullptr, NB * NSEQ, DIM, DIM, NSEQ, NSEQ, 0, DIM);
  // K rows: text -> kv 0..76, x -> kv 80..1103 (1104 rows/batch)
  gemm_bt<1, false><<<dim3(5, 8), 256, 0, stream>>>(
      xtb, Wkb, Kb, nullptr, NB * NP, DIM, DIM, NP, NKVR, 0, DIM);
  gemm_bt<1, false><<<dim3(64, 8), 256, 0, stream>>>(
      xb, Wkb, Kb, nullptr, NB * NSEQ, DIM, DIM, NSEQ, NKVR, 80, DIM);
  // V -> Vt transposed [b,h,d,kv]
  gemm_bt<2, false><<<dim3(5, 8), 256, 0, stream>>>(
      xtb, Wvb, Vtb, nullptr, NB * NP, DIM, DIM, NP, 0, 0, DIM);
  gemm_bt<2, false><<<dim3(64, 8), 256, 0, stream>>>(
      xb, Wvb, Vtb, nullptr, NB * NSEQ, DIM, DIM, NSEQ, 0, 80, DIM);

  attn_mfma<<<dim3(8, NB * NH), 256, 0, stream>>>(Qb, Kb, Vtb, gate, attnb);

  cast(Wp, Wpb, DIM * DIM);   // Wq slot is dead now
  ln_kernel<<<dim3(NB * NSEQ), 256, 0, stream>>>(attnb, lng, lnbt, lnob);
  gemm_bt<0, true><<<dim3(64, 8), 256, 0, stream>>>(
      lnob, Wpb, d_out, bp, NB * NSEQ, DIM, DIM, NSEQ, NSEQ, 0, DIM);
}